// Round 1
// baseline (279.844 us; speedup 1.0000x reference)
//
#include <hip/hip_runtime.h>

#define Bb 4
#define Cc 256
#define GC_ 64
#define Hh 128
#define Wd 128
#define HWn 16384
#define NPIX 65536
#define EPS 1e-5f

// workspace layout (float offsets); total ~68.2 MB
#define T_OFF   0
#define E_OFF   16777216
#define ST_OFF  (E_OFF + NPIX*4)
#define A_OFF   (ST_OFF + 16)
#define CV_OFF  (A_OFF + 16384)
#define FW_OFF  (CV_OFF + 256)
#define ALP_OFF (FW_OFF + 1024)
#define BET_OFF (ALP_OFF + 256)

// K0: A_g = qw_g^T @ kw_g ; cvec_g = qw_g^T (sum_r rk_g) ; fwred[o][i] = sum_c fusion_w[o, i*64+c]
__global__ __launch_bounds__(256) void k0_precompute(
    const float* __restrict__ qw, const float* __restrict__ kw,
    const float* __restrict__ rk0, const float* __restrict__ rk1,
    const float* __restrict__ rk2, const float* __restrict__ rk3,
    const float* __restrict__ fusion_w,
    float* __restrict__ A, float* __restrict__ cvec, float* __restrict__ fwred)
{
    const int tid = threadIdx.x;
    if (blockIdx.x == 4) {
        // fwred: thread o sums the 4 group blocks of its fusion row
        for (int i = 0; i < 4; ++i) {
            float s = 0.f;
            const float* fp = fusion_w + tid*256 + i*64;
            #pragma unroll 8
            for (int c = 0; c < 64; ++c) s += fp[c];
            fwred[tid*4 + i] = s;
        }
        return;
    }
    const int g = blockIdx.x;
    __shared__ float qwL[4096];
    __shared__ float kwL[4096];
    __shared__ float rks[64];
    for (int i = tid; i < 4096; i += 256) {
        qwL[i] = qw[g*4096 + i];
        kwL[i] = kw[g*4096 + i];
    }
    __syncthreads();
    if (tid < 64) {
        const float* rkp = (g==0)?rk0:(g==1)?rk1:(g==2)?rk2:rk3;
        const int R = 4*g + 9;               // 2L-1 for L={5,7,9,11}
        float s = 0.f;
        for (int r = 0; r < R; ++r) s += rkp[tid*R + r];
        rks[tid] = s;
    }
    __syncthreads();
    for (int idx = tid; idx < 4096; idx += 256) {
        const int c = idx >> 6, d = idx & 63;
        float s = 0.f;
        #pragma unroll
        for (int o = 0; o < 64; ++o) s += qwL[o*64 + c] * kwL[o*64 + d];
        A[g*4096 + idx] = s;
    }
    if (tid < 64) {
        float s = 0.f;
        #pragma unroll
        for (int o = 0; o < 64; ++o) s += qwL[o*64 + tid] * rks[o];
        cvec[g*64 + tid] = s;
    }
}

// K1: t[b, g*64+o, p] = sum_d A_g[o][d] * x[b, g*64+d, p]
__global__ __launch_bounds__(256) void k1_pointwise(
    const float* __restrict__ x, const float* __restrict__ A, float* __restrict__ t)
{
    __shared__ float AL[4096];
    const int tid = threadIdx.x;
    const int chunk = blockIdx.x & 63;
    const int g = (blockIdx.x >> 6) & 3;
    const int b = blockIdx.x >> 8;
    const float* Ag = A + g*4096;
    for (int i = tid; i < 4096; i += 256) AL[i] = Ag[i];
    __syncthreads();
    const int p = chunk*256 + tid;
    const float* xp = x + (size_t)(b*Cc + g*GC_)*HWn + p;
    float* tp       = t + (size_t)(b*Cc + g*GC_)*HWn + p;
    float xr[64];
    #pragma unroll
    for (int c = 0; c < 64; ++c) xr[c] = xp[c*HWn];
    for (int o = 0; o < 64; ++o) {
        const float4* a4 = (const float4*)(AL + o*64);
        float acc = 0.f;
        #pragma unroll
        for (int c4 = 0; c4 < 16; ++c4) {
            float4 a = a4[c4];
            acc += a.x*xr[4*c4] + a.y*xr[4*c4+1] + a.z*xr[4*c4+2] + a.w*xr[4*c4+3];
        }
        tp[o*HWn] = acc;
    }
}

// K2: S = vbox_L(t) + hbox_L(t) - t  (cross-shaped sum, zero padded), one (b,c) image per block
__global__ __launch_bounds__(256) void k2_cross(
    const float* __restrict__ t, float* __restrict__ S)
{
    __shared__ float timg[HWn];   // 64 KB
    const int tid = threadIdx.x;
    const int bc = blockIdx.x;
    const int g = (bc & 255) >> 6;
    const int p = g + 2;          // pad = (L-1)/2 = {2,3,4,5}
    const float4* src = (const float4*)(t + (size_t)bc*HWn);
    float4* dst = (float4*)timg;
    for (int i = tid; i < HWn/4; i += 256) dst[i] = src[i];
    __syncthreads();
    float* Sp = S + (size_t)bc*HWn;
    for (int idx = tid; idx < HWn; idx += 256) {
        const int h = idx >> 7, w = idx & 127;
        float s = -timg[idx];                       // center counted once total
        const int h0 = max(h-p, 0), h1 = min(h+p, 127);
        for (int hh = h0; hh <= h1; ++hh) s += timg[(hh<<7) + w];
        const int w0 = max(w-p, 0), w1 = min(w+p, 127);
        const int hb = h << 7;
        for (int ww = w0; ww <= w1; ++ww) s += timg[hb + ww];
        Sp[idx] = s;
    }
}

// K3: e[g] = sum_c (x_g+rq)·(S_g+cvec) ; accumulate mean/second-moment stats of e
__global__ __launch_bounds__(256) void k3_e(
    const float* __restrict__ x, const float* __restrict__ S,
    const float* __restrict__ r_q, const float* __restrict__ cvec,
    float* __restrict__ ebuf, float* __restrict__ stats)
{
    __shared__ float rqL[256], cvL[256];
    __shared__ float red[4*14];
    const int tid = threadIdx.x;
    rqL[tid] = r_q[tid];
    cvL[tid] = cvec[tid];
    __syncthreads();
    const int q = blockIdx.x*256 + tid;
    const int b = q >> 14, p = q & (HWn-1);
    float e4[4];
    #pragma unroll
    for (int g = 0; g < 4; ++g) {
        const float* xp = x + (size_t)(b*Cc + g*GC_)*HWn + p;
        const float* Sp = S + (size_t)(b*Cc + g*GC_)*HWn + p;
        float acc = 0.f;
        #pragma unroll 8
        for (int c = 0; c < 64; ++c)
            acc += (xp[c*HWn] + rqL[g*64 + c]) * (Sp[c*HWn] + cvL[g*64 + c]);
        e4[g] = acc;
    }
    ((float4*)ebuf)[q] = make_float4(e4[0], e4[1], e4[2], e4[3]);

    float v[14];
    v[0]=e4[0]; v[1]=e4[1]; v[2]=e4[2]; v[3]=e4[3];
    v[4]=e4[0]*e4[0]; v[5]=e4[0]*e4[1]; v[6]=e4[0]*e4[2]; v[7]=e4[0]*e4[3];
    v[8]=e4[1]*e4[1]; v[9]=e4[1]*e4[2]; v[10]=e4[1]*e4[3];
    v[11]=e4[2]*e4[2]; v[12]=e4[2]*e4[3]; v[13]=e4[3]*e4[3];
    #pragma unroll
    for (int kk = 0; kk < 14; ++kk) {
        float s = v[kk];
        for (int off = 32; off > 0; off >>= 1) s += __shfl_down(s, off, 64);
        v[kk] = s;
    }
    const int lane = tid & 63, wv = tid >> 6;
    if (lane == 0) {
        #pragma unroll
        for (int kk = 0; kk < 14; ++kk) red[wv*14 + kk] = v[kk];
    }
    __syncthreads();
    if (tid < 14) atomicAdd(&stats[tid], red[tid] + red[14+tid] + red[28+tid] + red[42+tid]);
}

// K4: fold BN into per-channel alpha/beta using fwred and the 4x4 moment matrix
__global__ __launch_bounds__(256) void k4_stats(
    const float* __restrict__ stats, const float* __restrict__ fwred,
    const float* __restrict__ gamma, const float* __restrict__ beta,
    float* __restrict__ alpha, float* __restrict__ beta2)
{
    const int o = threadIdx.x;
    const float invN = 1.f / (float)NPIX;
    const float me0 = stats[0]*invN, me1 = stats[1]*invN, me2 = stats[2]*invN, me3 = stats[3]*invN;
    const float m00 = stats[4]*invN,  m01 = stats[5]*invN,  m02 = stats[6]*invN,  m03 = stats[7]*invN;
    const float m11 = stats[8]*invN,  m12 = stats[9]*invN,  m13 = stats[10]*invN;
    const float m22 = stats[11]*invN, m23 = stats[12]*invN, m33 = stats[13]*invN;
    const float4 fw = ((const float4*)fwred)[o];
    const float Ef = fw.x*me0 + fw.y*me1 + fw.z*me2 + fw.w*me3;
    const float E2 = fw.x*fw.x*m00 + fw.y*fw.y*m11 + fw.z*fw.z*m22 + fw.w*fw.w*m33
                   + 2.f*(fw.x*fw.y*m01 + fw.x*fw.z*m02 + fw.x*fw.w*m03
                        + fw.y*fw.z*m12 + fw.y*fw.w*m13 + fw.z*fw.w*m23);
    const float var = E2 - Ef*Ef;
    const float a = gamma[o] * rsqrtf(var + EPS);
    alpha[o] = a;
    beta2[o] = beta[o] - Ef*a;
}

// K5: out = x * sigmoid(relu(alpha[o]*(fwred[o]·e) + beta2[o]))
__global__ __launch_bounds__(256) void k5_out(
    const float* __restrict__ x, const float* __restrict__ ebuf,
    const float* __restrict__ fwred, const float* __restrict__ alpha,
    const float* __restrict__ beta2, float* __restrict__ out)
{
    __shared__ float4 fwL[256];
    __shared__ float alL[256], beL[256];
    const int tid = threadIdx.x;
    fwL[tid] = ((const float4*)fwred)[tid];
    alL[tid] = alpha[tid];
    beL[tid] = beta2[tid];
    __syncthreads();
    const int q = blockIdx.x*256 + tid;
    const int b = q >> 14, p = q & (HWn-1);
    const float4 e4 = ((const float4*)ebuf)[q];
    const float* xp = x + (size_t)b*Cc*HWn + p;
    float* op = out + (size_t)b*Cc*HWn + p;
    #pragma unroll 4
    for (int o = 0; o < 256; ++o) {
        const float4 fw = fwL[o];
        const float f = fw.x*e4.x + fw.y*e4.y + fw.z*e4.z + fw.w*e4.w;
        float z = alL[o]*f + beL[o];
        z = fmaxf(z, 0.f);
        const float a = 1.f / (1.f + __expf(-z));
        op[o*HWn] = xp[o*HWn] * a;
    }
}

extern "C" void kernel_launch(void* const* d_in, const int* in_sizes, int n_in,
                              void* d_out, int out_size, void* d_ws, size_t ws_size,
                              hipStream_t stream)
{
    const float* x   = (const float*)d_in[0];
    const float* qw  = (const float*)d_in[1];
    const float* kw  = (const float*)d_in[2];
    const float* r_q = (const float*)d_in[3];
    const float* rk0 = (const float*)d_in[4];
    const float* rk1 = (const float*)d_in[5];
    const float* rk2 = (const float*)d_in[6];
    const float* rk3 = (const float*)d_in[7];
    const float* fw  = (const float*)d_in[8];
    const float* gm  = (const float*)d_in[9];
    const float* bt  = (const float*)d_in[10];
    float* out = (float*)d_out;
    float* ws  = (float*)d_ws;

    float* t     = ws + T_OFF;     // 67 MB
    float* ebuf  = ws + E_OFF;     // 1 MB
    float* stats = ws + ST_OFF;
    float* A     = ws + A_OFF;
    float* cvec  = ws + CV_OFF;
    float* fwr   = ws + FW_OFF;
    float* alpha = ws + ALP_OFF;
    float* beta2 = ws + BET_OFF;

    hipMemsetAsync(stats, 0, 16*sizeof(float), stream);
    k0_precompute<<<5,    256, 0, stream>>>(qw, kw, rk0, rk1, rk2, rk3, fw, A, cvec, fwr);
    k1_pointwise <<<1024, 256, 0, stream>>>(x, A, t);
    k2_cross     <<<1024, 256, 0, stream>>>(t, out);          // S staged in d_out
    k3_e         <<<256,  256, 0, stream>>>(x, out, r_q, cvec, ebuf, stats);
    k4_stats     <<<1,    256, 0, stream>>>(stats, fwr, gm, bt, alpha, beta2);
    k5_out       <<<256,  256, 0, stream>>>(x, ebuf, fwr, alpha, beta2, out);
}

// Round 2
// 193.763 us; speedup vs baseline: 1.4443x; 1.4443x over previous
//
#include <hip/hip_runtime.h>

#define Bb 4
#define Cc 256
#define GC_ 64
#define Hh 128
#define Wd 128
#define HWn 16384
#define NPIX 65536
#define EPS 1e-5f

// workspace layout (float offsets)
#define T_OFF   0
#define E_OFF   16777216
#define ST_OFF  (E_OFF + NPIX*4)
#define A_OFF   (ST_OFF + 16)
#define CV_OFF  (A_OFF + 16384)
#define FW_OFF  (CV_OFF + 256)
#define ALP_OFF (FW_OFF + 1024)
#define BET_OFF (ALP_OFF + 256)

// K0: A_g = qw_g^T @ kw_g ; cvec_g = qw_g^T (sum_r rk_g) ; fwred[o][i] = sum_c fusion_w[o, i*64+c]
__global__ __launch_bounds__(256) void k0_precompute(
    const float* __restrict__ qw, const float* __restrict__ kw,
    const float* __restrict__ rk0, const float* __restrict__ rk1,
    const float* __restrict__ rk2, const float* __restrict__ rk3,
    const float* __restrict__ fusion_w,
    float* __restrict__ A, float* __restrict__ cvec, float* __restrict__ fwred)
{
    const int tid = threadIdx.x;
    if (blockIdx.x == 4) {
        for (int i = 0; i < 4; ++i) {
            float s = 0.f;
            const float* fp = fusion_w + tid*256 + i*64;
            #pragma unroll 8
            for (int c = 0; c < 64; ++c) s += fp[c];
            fwred[tid*4 + i] = s;
        }
        return;
    }
    const int g = blockIdx.x;
    __shared__ float qwL[4096];
    __shared__ float kwL[4096];
    __shared__ float rks[64];
    for (int i = tid; i < 4096; i += 256) {
        qwL[i] = qw[g*4096 + i];
        kwL[i] = kw[g*4096 + i];
    }
    __syncthreads();
    if (tid < 64) {
        const float* rkp = (g==0)?rk0:(g==1)?rk1:(g==2)?rk2:rk3;
        const int R = 4*g + 9;               // 2L-1 for L={5,7,9,11}
        float s = 0.f;
        for (int r = 0; r < R; ++r) s += rkp[tid*R + r];
        rks[tid] = s;
    }
    __syncthreads();
    for (int idx = tid; idx < 4096; idx += 256) {
        const int c = idx >> 6, d = idx & 63;
        float s = 0.f;
        #pragma unroll
        for (int o = 0; o < 64; ++o) s += qwL[o*64 + c] * kwL[o*64 + d];
        A[g*4096 + idx] = s;
    }
    if (tid < 64) {
        float s = 0.f;
        #pragma unroll
        for (int o = 0; o < 64; ++o) s += qwL[o*64 + tid] * rks[o];
        cvec[g*64 + tid] = s;
    }
}

// K1: t[b, g*64+o, p] = sum_d A_g[o][d] * x[b, g*64+d, p]
__global__ __launch_bounds__(256) void k1_pointwise(
    const float* __restrict__ x, const float* __restrict__ A, float* __restrict__ t)
{
    __shared__ float AL[4096];
    const int tid = threadIdx.x;
    const int chunk = blockIdx.x & 63;
    const int g = (blockIdx.x >> 6) & 3;
    const int b = blockIdx.x >> 8;
    const float* Ag = A + g*4096;
    for (int i = tid; i < 4096; i += 256) AL[i] = Ag[i];
    __syncthreads();
    const int p = chunk*256 + tid;
    const float* xp = x + (size_t)(b*Cc + g*GC_)*HWn + p;
    float* tp       = t + (size_t)(b*Cc + g*GC_)*HWn + p;
    float xr[64];
    #pragma unroll
    for (int c = 0; c < 64; ++c) xr[c] = xp[c*HWn];
    for (int o = 0; o < 64; ++o) {
        const float4* a4 = (const float4*)(AL + o*64);
        float acc = 0.f;
        #pragma unroll
        for (int c4 = 0; c4 < 16; ++c4) {
            float4 a = a4[c4];
            acc += a.x*xr[4*c4] + a.y*xr[4*c4+1] + a.z*xr[4*c4+2] + a.w*xr[4*c4+3];
        }
        tp[o*HWn] = acc;
    }
}

// K2: S = vbox_L(t) + hbox_L(t) - t via O(1) sliding windows.
// One 32-row tile of one (b,c) image per block. LDS 39KB -> 4 blocks/CU.
#define TROW 132   // padded LDS row stride (132 mod 32 = 4 banks -> row-conflict-free)
__global__ __launch_bounds__(256) void k2_cross(
    const float* __restrict__ t, float* __restrict__ S)
{
    __shared__ float timg[42*TROW];   // staged rows [h0-p, h0+31+p], zero-filled OOB
    __shared__ float simg[32*TROW];   // Sv then final S
    const int tid = threadIdx.x;
    const int tile = blockIdx.x & 3;
    const int bc = blockIdx.x >> 2;
    const int g = (bc & 255) >> 6;
    const int p = g + 2;              // pad = {2,3,4,5}
    const int h0 = tile * 32;
    const int nrows = 32 + 2*p;
    const float* tp = t + (size_t)bc*HWn;

    // stage t rows (zero-fill rows outside image -> no boundary guards later)
    for (int idx = tid; idx < nrows*128; idx += 256) {
        const int r = idx >> 7, w = idx & 127;
        const int hh = h0 - p + r;
        timg[r*TROW + w] = (hh >= 0 && hh < 128) ? tp[(hh<<7) + w] : 0.f;
    }
    __syncthreads();

    // vertical sliding box: 128 cols x 2 halves, 16 output rows each
    {
        const int w = tid & 127;
        const int half = tid >> 7;
        const int rbase = half * 16;      // LDS row of first output's (h-p)
        float run = 0.f;
        for (int j = 0; j <= 2*p; ++j) run += timg[(rbase + j)*TROW + w];
        #pragma unroll
        for (int i = 0; i < 16; ++i) {
            simg[(rbase + i)*TROW + w] = run;
            if (i != 15)
                run += timg[(rbase + i + 1 + 2*p)*TROW + w] - timg[(rbase + i)*TROW + w];
        }
    }
    __syncthreads();

    // horizontal sliding box + combine: 32 rows x 8 segments of 16 cols
    {
        const int r8 = tid >> 3;          // 0..31 output row (h0+r8)
        const int seg = tid & 7;
        const int w0 = seg * 16;
        const float* trow = timg + (r8 + p)*TROW;
        float run = 0.f;
        const int lo = max(w0 - p, 0), hi = min(w0 + p, 127);
        for (int ww = lo; ww <= hi; ++ww) run += trow[ww];
        #pragma unroll
        for (int j = 0; j < 16; ++j) {
            const int w = w0 + j;
            const float sv = simg[r8*TROW + w];
            simg[r8*TROW + w] = run + sv - trow[w];
            run += (w + 1 + p < 128 ? trow[w + 1 + p] : 0.f)
                 - (w - p     >= 0  ? trow[w - p]     : 0.f);
        }
    }
    __syncthreads();

    float* Sp = S + (size_t)bc*HWn;
    for (int idx = tid; idx < 32*128; idx += 256) {
        const int r = idx >> 7, w = idx & 127;
        Sp[((h0 + r) << 7) + w] = simg[r*TROW + w];
    }
}

// K3: e[b,g,p] = sum_c (x_c+rq_c)(S_c+cv_c), planar output; one (b,g,chunk) per block
__global__ __launch_bounds__(256) void k3_e(
    const float* __restrict__ x, const float* __restrict__ S,
    const float* __restrict__ r_q, const float* __restrict__ cvec,
    float* __restrict__ ebuf)
{
    const int tid = threadIdx.x;
    const int chunk = blockIdx.x & 63;
    const int g = (blockIdx.x >> 6) & 3;
    const int b = blockIdx.x >> 8;
    __shared__ float rqL[64], cvL[64];
    if (tid < 64) { rqL[tid] = r_q[g*64 + tid]; cvL[tid] = cvec[g*64 + tid]; }
    __syncthreads();
    const int p = chunk*256 + tid;
    const float* xp = x + (size_t)(b*Cc + g*GC_)*HWn + p;
    const float* Sp = S + (size_t)(b*Cc + g*GC_)*HWn + p;
    float acc = 0.f;
    #pragma unroll 16
    for (int c = 0; c < 64; ++c)
        acc += (xp[c*HWn] + rqL[c]) * (Sp[c*HWn] + cvL[c]);
    ebuf[(b*4 + g)*HWn + p] = acc;
}

// K3b: 4x4 moment matrix of e (14 scalars) via block reduce + atomics
__global__ __launch_bounds__(256) void k3b_stats(
    const float* __restrict__ ebuf, float* __restrict__ stats)
{
    __shared__ float red[4*14];
    const int tid = threadIdx.x;
    const int q = blockIdx.x*256 + tid;
    const int b = q >> 14, p = q & (HWn - 1);
    const float* eb = ebuf + (size_t)b*4*HWn;
    const float e0 = eb[0*HWn + p], e1 = eb[1*HWn + p], e2 = eb[2*HWn + p], e3 = eb[3*HWn + p];
    float v[14];
    v[0]=e0; v[1]=e1; v[2]=e2; v[3]=e3;
    v[4]=e0*e0; v[5]=e0*e1; v[6]=e0*e2; v[7]=e0*e3;
    v[8]=e1*e1; v[9]=e1*e2; v[10]=e1*e3;
    v[11]=e2*e2; v[12]=e2*e3; v[13]=e3*e3;
    #pragma unroll
    for (int kk = 0; kk < 14; ++kk) {
        float s = v[kk];
        for (int off = 32; off > 0; off >>= 1) s += __shfl_down(s, off, 64);
        v[kk] = s;
    }
    const int lane = tid & 63, wv = tid >> 6;
    if (lane == 0) {
        #pragma unroll
        for (int kk = 0; kk < 14; ++kk) red[wv*14 + kk] = v[kk];
    }
    __syncthreads();
    if (tid < 14) atomicAdd(&stats[tid], red[tid] + red[14+tid] + red[28+tid] + red[42+tid]);
}

// K4: fold BN into per-channel alpha/beta
__global__ __launch_bounds__(256) void k4_stats(
    const float* __restrict__ stats, const float* __restrict__ fwred,
    const float* __restrict__ gamma, const float* __restrict__ beta,
    float* __restrict__ alpha, float* __restrict__ beta2)
{
    const int o = threadIdx.x;
    const float invN = 1.f / (float)NPIX;
    const float me0 = stats[0]*invN, me1 = stats[1]*invN, me2 = stats[2]*invN, me3 = stats[3]*invN;
    const float m00 = stats[4]*invN,  m01 = stats[5]*invN,  m02 = stats[6]*invN,  m03 = stats[7]*invN;
    const float m11 = stats[8]*invN,  m12 = stats[9]*invN,  m13 = stats[10]*invN;
    const float m22 = stats[11]*invN, m23 = stats[12]*invN, m33 = stats[13]*invN;
    const float4 fw = ((const float4*)fwred)[o];
    const float Ef = fw.x*me0 + fw.y*me1 + fw.z*me2 + fw.w*me3;
    const float E2 = fw.x*fw.x*m00 + fw.y*fw.y*m11 + fw.z*fw.z*m22 + fw.w*fw.w*m33
                   + 2.f*(fw.x*fw.y*m01 + fw.x*fw.z*m02 + fw.x*fw.w*m03
                        + fw.y*fw.z*m12 + fw.y*fw.w*m13 + fw.z*fw.w*m23);
    const float var = E2 - Ef*Ef;
    const float a = gamma[o] * rsqrtf(var + EPS);
    alpha[o] = a;
    beta2[o] = beta[o] - Ef*a;
}

// K5: out = x * sigmoid(relu(alpha[o]*(fwred[o]·e) + beta2[o]))
// block -> (b, o, chunk of 1024 px), 4 px/thread via float4. ebuf re-reads are L2-resident.
__global__ __launch_bounds__(256) void k5_out(
    const float* __restrict__ x, const float* __restrict__ ebuf,
    const float* __restrict__ fwred, const float* __restrict__ alpha,
    const float* __restrict__ beta2, float* __restrict__ out)
{
    const int chunk = blockIdx.x & 15;
    const int o = (blockIdx.x >> 4) & 255;
    const int b = blockIdx.x >> 12;
    const float4 fw = ((const float4*)fwred)[o];
    const float al = alpha[o], be = beta2[o];
    const int p0 = chunk*1024 + threadIdx.x*4;
    const float* eb = ebuf + (size_t)b*4*HWn;
    const float4 E0 = *(const float4*)(eb + 0*HWn + p0);
    const float4 E1 = *(const float4*)(eb + 1*HWn + p0);
    const float4 E2 = *(const float4*)(eb + 2*HWn + p0);
    const float4 E3 = *(const float4*)(eb + 3*HWn + p0);
    const size_t base = (size_t)(b*Cc + o)*HWn + p0;
    const float4 xv = *(const float4*)(x + base);
    float f[4], xa[4] = {xv.x, xv.y, xv.z, xv.w};
    f[0] = fw.x*E0.x + fw.y*E1.x + fw.z*E2.x + fw.w*E3.x;
    f[1] = fw.x*E0.y + fw.y*E1.y + fw.z*E2.y + fw.w*E3.y;
    f[2] = fw.x*E0.z + fw.y*E1.z + fw.z*E2.z + fw.w*E3.z;
    f[3] = fw.x*E0.w + fw.y*E1.w + fw.z*E2.w + fw.w*E3.w;
    float4 r;
    float* rp = &r.x;
    #pragma unroll
    for (int j = 0; j < 4; ++j) {
        float z = al*f[j] + be;
        z = fmaxf(z, 0.f);
        rp[j] = xa[j] / (1.f + __expf(-z));
    }
    *(float4*)(out + base) = r;
}

extern "C" void kernel_launch(void* const* d_in, const int* in_sizes, int n_in,
                              void* d_out, int out_size, void* d_ws, size_t ws_size,
                              hipStream_t stream)
{
    const float* x   = (const float*)d_in[0];
    const float* qw  = (const float*)d_in[1];
    const float* kw  = (const float*)d_in[2];
    const float* r_q = (const float*)d_in[3];
    const float* rk0 = (const float*)d_in[4];
    const float* rk1 = (const float*)d_in[5];
    const float* rk2 = (const float*)d_in[6];
    const float* rk3 = (const float*)d_in[7];
    const float* fw  = (const float*)d_in[8];
    const float* gm  = (const float*)d_in[9];
    const float* bt  = (const float*)d_in[10];
    float* out = (float*)d_out;
    float* ws  = (float*)d_ws;

    float* t     = ws + T_OFF;
    float* ebuf  = ws + E_OFF;
    float* stats = ws + ST_OFF;
    float* A     = ws + A_OFF;
    float* cvec  = ws + CV_OFF;
    float* fwr   = ws + FW_OFF;
    float* alpha = ws + ALP_OFF;
    float* beta2 = ws + BET_OFF;

    hipMemsetAsync(stats, 0, 16*sizeof(float), stream);
    k0_precompute<<<5,     256, 0, stream>>>(qw, kw, rk0, rk1, rk2, rk3, fw, A, cvec, fwr);
    k1_pointwise <<<1024,  256, 0, stream>>>(x, A, t);
    k2_cross     <<<4096,  256, 0, stream>>>(t, out);          // S staged in d_out
    k3_e         <<<1024,  256, 0, stream>>>(x, out, r_q, cvec, ebuf);
    k3b_stats    <<<256,   256, 0, stream>>>(ebuf, stats);
    k4_stats     <<<1,     256, 0, stream>>>(stats, fwr, gm, bt, alpha, beta2);
    k5_out       <<<16384, 256, 0, stream>>>(x, ebuf, fwr, alpha, beta2, out);
}

// Round 3
// 159.943 us; speedup vs baseline: 1.7496x; 1.2114x over previous
//
#include <hip/hip_runtime.h>

#define Bb 4
#define Cc 256
#define GC_ 64
#define Hh 128
#define Wd 128
#define HWn 16384
#define NPIX 65536
#define EPS 1e-5f

// workspace layout (float offsets)
#define T_OFF   0
#define E_OFF   16777216
#define ST_OFF  (E_OFF + NPIX*4)
#define A_OFF   (ST_OFF + 16)
#define CV_OFF  (A_OFF + 16384)
#define FW_OFF  (CV_OFF + 256)
#define ALP_OFF (FW_OFF + 1024)
#define BET_OFF (ALP_OFF + 256)

typedef __attribute__((ext_vector_type(8))) short short8v;
typedef __attribute__((ext_vector_type(4))) float f32x4;

__device__ inline unsigned short f2bf(float f) {
    union { float f; unsigned u; } v; v.f = f;
    unsigned r = v.u + 0x7fff + ((v.u >> 16) & 1);   // RNE
    return (unsigned short)(r >> 16);
}

// K0: A_g = qw_g^T @ kw_g ; cvec_g = qw_g^T (sum_r rk_g) ; fwred[o][i] = sum_c fusion_w[o, i*64+c]
__global__ __launch_bounds__(256) void k0_precompute(
    const float* __restrict__ qw, const float* __restrict__ kw,
    const float* __restrict__ rk0, const float* __restrict__ rk1,
    const float* __restrict__ rk2, const float* __restrict__ rk3,
    const float* __restrict__ fusion_w,
    float* __restrict__ A, float* __restrict__ cvec, float* __restrict__ fwred)
{
    const int tid = threadIdx.x;
    if (blockIdx.x == 4) {
        for (int i = 0; i < 4; ++i) {
            float s = 0.f;
            const float* fp = fusion_w + tid*256 + i*64;
            #pragma unroll 8
            for (int c = 0; c < 64; ++c) s += fp[c];
            fwred[tid*4 + i] = s;
        }
        return;
    }
    const int g = blockIdx.x;
    __shared__ float qwL[4096];
    __shared__ float kwL[4096];
    __shared__ float rks[64];
    for (int i = tid; i < 4096; i += 256) {
        qwL[i] = qw[g*4096 + i];
        kwL[i] = kw[g*4096 + i];
    }
    __syncthreads();
    if (tid < 64) {
        const float* rkp = (g==0)?rk0:(g==1)?rk1:(g==2)?rk2:rk3;
        const int R = 4*g + 9;               // 2L-1 for L={5,7,9,11}
        float s = 0.f;
        for (int r = 0; r < R; ++r) s += rkp[tid*R + r];
        rks[tid] = s;
    }
    __syncthreads();
    for (int idx = tid; idx < 4096; idx += 256) {
        const int c = idx >> 6, d = idx & 63;
        float s = 0.f;
        #pragma unroll
        for (int o = 0; o < 64; ++o) s += qwL[o*64 + c] * kwL[o*64 + d];
        A[g*4096 + idx] = s;
    }
    if (tid < 64) {
        float s = 0.f;
        #pragma unroll
        for (int o = 0; o < 64; ++o) s += qwL[o*64 + tid] * rks[o];
        cvec[g*64 + tid] = s;
    }
}

// K1 (MFMA): t[b, g*64+o, p] = sum_d A_g[o][d] * x[b, g*64+d, p]
// Per (b,g): C[64,16384] = A[64,64] x X[64,16384], bf16 inputs, fp32 acc/out.
// Wave owns 64 px (4 n-tiles of 16). A-frag: lane holds A[m*16+(l&15)][kh*32+(l>>4)*8+j].
// B-frag: lane holds X[kh*32+(l>>4)*8+j][px0+nt*16+(l&15)].
// D: row=(l>>4)*4+r, col=l&15 (m89-verified mapping).
__global__ __launch_bounds__(256) void k1_mfma(
    const float* __restrict__ x, const float* __restrict__ A, float* __restrict__ t)
{
    const int tid = threadIdx.x;
    const int wv = tid >> 6, lane = tid & 63;
    const int chunk = blockIdx.x & 63;
    const int g = (blockIdx.x >> 6) & 3;
    const int b = blockIdx.x >> 8;
    const int l15 = lane & 15, lg = lane >> 4;

    const float* Ag = A + g*4096;
    short8v afr[4][2];
    #pragma unroll
    for (int m = 0; m < 4; ++m)
      #pragma unroll
      for (int kh = 0; kh < 2; ++kh) {
        const float* ap = Ag + (m*16 + l15)*64 + kh*32 + lg*8;
        #pragma unroll
        for (int j = 0; j < 8; ++j) afr[m][kh][j] = (short)f2bf(ap[j]);
      }

    const int px0 = chunk*256 + wv*64;
    const float* xg = x + (size_t)(b*Cc + g*GC_)*HWn;
    float* tg       = t + (size_t)(b*Cc + g*GC_)*HWn;

    #pragma unroll
    for (int nt = 0; nt < 4; ++nt) {
        const int pn = px0 + nt*16 + l15;
        short8v bfr[2];
        #pragma unroll
        for (int kh = 0; kh < 2; ++kh) {
            const float* xp = xg + (size_t)(kh*32 + lg*8)*HWn + pn;
            #pragma unroll
            for (int j = 0; j < 8; ++j) bfr[kh][j] = (short)f2bf(xp[j*HWn]);
        }
        #pragma unroll
        for (int m = 0; m < 4; ++m) {
            f32x4 acc = {0.f, 0.f, 0.f, 0.f};
            acc = __builtin_amdgcn_mfma_f32_16x16x32_bf16(afr[m][0], bfr[0], acc, 0, 0, 0);
            acc = __builtin_amdgcn_mfma_f32_16x16x32_bf16(afr[m][1], bfr[1], acc, 0, 0, 0);
            float* tp = tg + (size_t)(m*16 + lg*4)*HWn + pn;
            #pragma unroll
            for (int r = 0; r < 4; ++r) tp[r*HWn] = acc[r];
        }
    }
}

// K2: S = vbox_L(t) + hbox_L(t) - t via O(1) sliding windows.
// One 32-row tile of one (b,c) image per block. LDS 39KB -> 4 blocks/CU.
#define TROW 132
__global__ __launch_bounds__(256) void k2_cross(
    const float* __restrict__ t, float* __restrict__ S)
{
    __shared__ float timg[42*TROW];
    __shared__ float simg[32*TROW];
    const int tid = threadIdx.x;
    const int tile = blockIdx.x & 3;
    const int bc = blockIdx.x >> 2;
    const int g = (bc & 255) >> 6;
    const int p = g + 2;              // pad = {2,3,4,5}
    const int h0 = tile * 32;
    const int nrows = 32 + 2*p;
    const float* tp = t + (size_t)bc*HWn;

    for (int idx = tid; idx < nrows*128; idx += 256) {
        const int r = idx >> 7, w = idx & 127;
        const int hh = h0 - p + r;
        timg[r*TROW + w] = (hh >= 0 && hh < 128) ? tp[(hh<<7) + w] : 0.f;
    }
    __syncthreads();

    {
        const int w = tid & 127;
        const int half = tid >> 7;
        const int rbase = half * 16;
        float run = 0.f;
        for (int j = 0; j <= 2*p; ++j) run += timg[(rbase + j)*TROW + w];
        #pragma unroll
        for (int i = 0; i < 16; ++i) {
            simg[(rbase + i)*TROW + w] = run;
            if (i != 15)
                run += timg[(rbase + i + 1 + 2*p)*TROW + w] - timg[(rbase + i)*TROW + w];
        }
    }
    __syncthreads();

    {
        const int r8 = tid >> 3;
        const int seg = tid & 7;
        const int w0 = seg * 16;
        const float* trow = timg + (r8 + p)*TROW;
        float run = 0.f;
        const int lo = max(w0 - p, 0), hi = min(w0 + p, 127);
        for (int ww = lo; ww <= hi; ++ww) run += trow[ww];
        #pragma unroll
        for (int j = 0; j < 16; ++j) {
            const int w = w0 + j;
            const float sv = simg[r8*TROW + w];
            simg[r8*TROW + w] = run + sv - trow[w];
            run += (w + 1 + p < 128 ? trow[w + 1 + p] : 0.f)
                 - (w - p     >= 0  ? trow[w - p]     : 0.f);
        }
    }
    __syncthreads();

    float* Sp = S + (size_t)bc*HWn;
    for (int idx = tid; idx < 32*128; idx += 256) {
        const int r = idx >> 7, w = idx & 127;
        Sp[((h0 + r) << 7) + w] = simg[r*TROW + w];
    }
}

// K3: e[b,g,p] = sum_c (x_c+rq_c)(S_c+cv_c), planar output
__global__ __launch_bounds__(256) void k3_e(
    const float* __restrict__ x, const float* __restrict__ S,
    const float* __restrict__ r_q, const float* __restrict__ cvec,
    float* __restrict__ ebuf)
{
    const int tid = threadIdx.x;
    const int chunk = blockIdx.x & 63;
    const int g = (blockIdx.x >> 6) & 3;
    const int b = blockIdx.x >> 8;
    __shared__ float rqL[64], cvL[64];
    if (tid < 64) { rqL[tid] = r_q[g*64 + tid]; cvL[tid] = cvec[g*64 + tid]; }
    __syncthreads();
    const int p = chunk*256 + tid;
    const float* xp = x + (size_t)(b*Cc + g*GC_)*HWn + p;
    const float* Sp = S + (size_t)(b*Cc + g*GC_)*HWn + p;
    float acc = 0.f;
    #pragma unroll 16
    for (int c = 0; c < 64; ++c)
        acc += (xp[c*HWn] + rqL[c]) * (Sp[c*HWn] + cvL[c]);
    ebuf[(b*4 + g)*HWn + p] = acc;
}

// K3b: 4x4 moment matrix of e (14 scalars)
__global__ __launch_bounds__(256) void k3b_stats(
    const float* __restrict__ ebuf, float* __restrict__ stats)
{
    __shared__ float red[4*14];
    const int tid = threadIdx.x;
    const int q = blockIdx.x*256 + tid;
    const int b = q >> 14, p = q & (HWn - 1);
    const float* eb = ebuf + (size_t)b*4*HWn;
    const float e0 = eb[0*HWn + p], e1 = eb[1*HWn + p], e2 = eb[2*HWn + p], e3 = eb[3*HWn + p];
    float v[14];
    v[0]=e0; v[1]=e1; v[2]=e2; v[3]=e3;
    v[4]=e0*e0; v[5]=e0*e1; v[6]=e0*e2; v[7]=e0*e3;
    v[8]=e1*e1; v[9]=e1*e2; v[10]=e1*e3;
    v[11]=e2*e2; v[12]=e2*e3; v[13]=e3*e3;
    #pragma unroll
    for (int kk = 0; kk < 14; ++kk) {
        float s = v[kk];
        for (int off = 32; off > 0; off >>= 1) s += __shfl_down(s, off, 64);
        v[kk] = s;
    }
    const int lane = tid & 63, wv = tid >> 6;
    if (lane == 0) {
        #pragma unroll
        for (int kk = 0; kk < 14; ++kk) red[wv*14 + kk] = v[kk];
    }
    __syncthreads();
    if (tid < 14) atomicAdd(&stats[tid], red[tid] + red[14+tid] + red[28+tid] + red[42+tid]);
}

// K4: fold BN into per-channel alpha/beta
__global__ __launch_bounds__(256) void k4_stats(
    const float* __restrict__ stats, const float* __restrict__ fwred,
    const float* __restrict__ gamma, const float* __restrict__ beta,
    float* __restrict__ alpha, float* __restrict__ beta2)
{
    const int o = threadIdx.x;
    const float invN = 1.f / (float)NPIX;
    const float me0 = stats[0]*invN, me1 = stats[1]*invN, me2 = stats[2]*invN, me3 = stats[3]*invN;
    const float m00 = stats[4]*invN,  m01 = stats[5]*invN,  m02 = stats[6]*invN,  m03 = stats[7]*invN;
    const float m11 = stats[8]*invN,  m12 = stats[9]*invN,  m13 = stats[10]*invN;
    const float m22 = stats[11]*invN, m23 = stats[12]*invN, m33 = stats[13]*invN;
    const float4 fw = ((const float4*)fwred)[o];
    const float Ef = fw.x*me0 + fw.y*me1 + fw.z*me2 + fw.w*me3;
    const float E2 = fw.x*fw.x*m00 + fw.y*fw.y*m11 + fw.z*fw.z*m22 + fw.w*fw.w*m33
                   + 2.f*(fw.x*fw.y*m01 + fw.x*fw.z*m02 + fw.x*fw.w*m03
                        + fw.y*fw.z*m12 + fw.y*fw.w*m13 + fw.z*fw.w*m23);
    const float var = E2 - Ef*Ef;
    const float a = gamma[o] * rsqrtf(var + EPS);
    alpha[o] = a;
    beta2[o] = beta[o] - Ef*a;
}

// K5: out = x * sigmoid(relu(alpha[o]*(fwred[o]·e) + beta2[o]))
__global__ __launch_bounds__(256) void k5_out(
    const float* __restrict__ x, const float* __restrict__ ebuf,
    const float* __restrict__ fwred, const float* __restrict__ alpha,
    const float* __restrict__ beta2, float* __restrict__ out)
{
    const int chunk = blockIdx.x & 15;
    const int o = (blockIdx.x >> 4) & 255;
    const int b = blockIdx.x >> 12;
    const float4 fw = ((const float4*)fwred)[o];
    const float al = alpha[o], be = beta2[o];
    const int p0 = chunk*1024 + threadIdx.x*4;
    const float* eb = ebuf + (size_t)b*4*HWn;
    const float4 E0 = *(const float4*)(eb + 0*HWn + p0);
    const float4 E1 = *(const float4*)(eb + 1*HWn + p0);
    const float4 E2 = *(const float4*)(eb + 2*HWn + p0);
    const float4 E3 = *(const float4*)(eb + 3*HWn + p0);
    const size_t base = (size_t)(b*Cc + o)*HWn + p0;
    const float4 xv = *(const float4*)(x + base);
    float f[4], xa[4] = {xv.x, xv.y, xv.z, xv.w};
    f[0] = fw.x*E0.x + fw.y*E1.x + fw.z*E2.x + fw.w*E3.x;
    f[1] = fw.x*E0.y + fw.y*E1.y + fw.z*E2.y + fw.w*E3.y;
    f[2] = fw.x*E0.z + fw.y*E1.z + fw.z*E2.z + fw.w*E3.z;
    f[3] = fw.x*E0.w + fw.y*E1.w + fw.z*E2.w + fw.w*E3.w;
    float4 r;
    float* rp = &r.x;
    #pragma unroll
    for (int j = 0; j < 4; ++j) {
        float z = al*f[j] + be;
        z = fmaxf(z, 0.f);
        rp[j] = xa[j] / (1.f + __expf(-z));
    }
    *(float4*)(out + base) = r;
}

extern "C" void kernel_launch(void* const* d_in, const int* in_sizes, int n_in,
                              void* d_out, int out_size, void* d_ws, size_t ws_size,
                              hipStream_t stream)
{
    const float* x   = (const float*)d_in[0];
    const float* qw  = (const float*)d_in[1];
    const float* kw  = (const float*)d_in[2];
    const float* r_q = (const float*)d_in[3];
    const float* rk0 = (const float*)d_in[4];
    const float* rk1 = (const float*)d_in[5];
    const float* rk2 = (const float*)d_in[6];
    const float* rk3 = (const float*)d_in[7];
    const float* fw  = (const float*)d_in[8];
    const float* gm  = (const float*)d_in[9];
    const float* bt  = (const float*)d_in[10];
    float* out = (float*)d_out;
    float* ws  = (float*)d_ws;

    float* t     = ws + T_OFF;
    float* ebuf  = ws + E_OFF;
    float* stats = ws + ST_OFF;
    float* A     = ws + A_OFF;
    float* cvec  = ws + CV_OFF;
    float* fwr   = ws + FW_OFF;
    float* alpha = ws + ALP_OFF;
    float* beta2 = ws + BET_OFF;

    hipMemsetAsync(stats, 0, 16*sizeof(float), stream);
    k0_precompute<<<5,     256, 0, stream>>>(qw, kw, rk0, rk1, rk2, rk3, fw, A, cvec, fwr);
    k1_mfma      <<<1024,  256, 0, stream>>>(x, A, t);
    k2_cross     <<<4096,  256, 0, stream>>>(t, out);          // S staged in d_out
    k3_e         <<<1024,  256, 0, stream>>>(x, out, r_q, cvec, ebuf);
    k3b_stats    <<<256,   256, 0, stream>>>(ebuf, stats);
    k4_stats     <<<1,     256, 0, stream>>>(stats, fwr, gm, bt, alpha, beta2);
    k5_out       <<<16384, 256, 0, stream>>>(x, ebuf, fwr, alpha, beta2, out);
}

// Round 4
// 134.919 us; speedup vs baseline: 2.0742x; 1.1855x over previous
//
#include <hip/hip_runtime.h>

#define Bb 4
#define Cc 256
#define GC_ 64
#define Hh 128
#define Wd 128
#define HWn 16384
#define NPIX 65536
#define EPS 1e-5f

// workspace layout (float offsets). t is bf16 now (uses half its region).
#define T_OFF   0
#define E_OFF   16777216
#define ST_OFF  (E_OFF + NPIX*4)
#define A_OFF   (ST_OFF + 16)
#define CV_OFF  (A_OFF + 16384)
#define FW_OFF  (CV_OFF + 256)
#define ALP_OFF (FW_OFF + 1024)
#define BET_OFF (ALP_OFF + 256)

typedef __attribute__((ext_vector_type(8))) short short8v;
typedef __attribute__((ext_vector_type(4))) float f32x4;
typedef unsigned short u16;

__device__ inline u16 f2bf(float f) {
    union { float f; unsigned u; } v; v.f = f;
    unsigned r = v.u + 0x7fff + ((v.u >> 16) & 1);   // RNE
    return (u16)(r >> 16);
}
__device__ inline float bf2f(u16 u) {
    union { unsigned u; float f; } v; v.u = ((unsigned)u) << 16;
    return v.f;
}

// K0: A_g = qw_g^T @ kw_g ; cvec_g = qw_g^T (sum_r rk_g) ; fwred[o][i] = sum_c fusion_w[o, i*64+c]
__global__ __launch_bounds__(256) void k0_precompute(
    const float* __restrict__ qw, const float* __restrict__ kw,
    const float* __restrict__ rk0, const float* __restrict__ rk1,
    const float* __restrict__ rk2, const float* __restrict__ rk3,
    const float* __restrict__ fusion_w,
    float* __restrict__ A, float* __restrict__ cvec, float* __restrict__ fwred)
{
    const int tid = threadIdx.x;
    if (blockIdx.x == 4) {
        for (int i = 0; i < 4; ++i) {
            float s = 0.f;
            const float* fp = fusion_w + tid*256 + i*64;
            #pragma unroll 8
            for (int c = 0; c < 64; ++c) s += fp[c];
            fwred[tid*4 + i] = s;
        }
        return;
    }
    const int g = blockIdx.x;
    __shared__ float qwL[4096];
    __shared__ float kwL[4096];
    __shared__ float rks[64];
    for (int i = tid; i < 4096; i += 256) {
        qwL[i] = qw[g*4096 + i];
        kwL[i] = kw[g*4096 + i];
    }
    __syncthreads();
    if (tid < 64) {
        const float* rkp = (g==0)?rk0:(g==1)?rk1:(g==2)?rk2:rk3;
        const int R = 4*g + 9;               // 2L-1 for L={5,7,9,11}
        float s = 0.f;
        for (int r = 0; r < R; ++r) s += rkp[tid*R + r];
        rks[tid] = s;
    }
    __syncthreads();
    for (int idx = tid; idx < 4096; idx += 256) {
        const int c = idx >> 6, d = idx & 63;
        float s = 0.f;
        #pragma unroll
        for (int o = 0; o < 64; ++o) s += qwL[o*64 + c] * kwL[o*64 + d];
        A[g*4096 + idx] = s;
    }
    if (tid < 64) {
        float s = 0.f;
        #pragma unroll
        for (int o = 0; o < 64; ++o) s += qwL[o*64 + tid] * rks[o];
        cvec[g*64 + tid] = s;
    }
}

// K1 (MFMA): t[b, g*64+o, p] = sum_d A_g[o][d] * x[b, g*64+d, p], t stored bf16
__global__ __launch_bounds__(256) void k1_mfma(
    const float* __restrict__ x, const float* __restrict__ A, u16* __restrict__ t)
{
    const int tid = threadIdx.x;
    const int wv = tid >> 6, lane = tid & 63;
    const int chunk = blockIdx.x & 63;
    const int g = (blockIdx.x >> 6) & 3;
    const int b = blockIdx.x >> 8;
    const int l15 = lane & 15, lg = lane >> 4;

    const float* Ag = A + g*4096;
    short8v afr[4][2];
    #pragma unroll
    for (int m = 0; m < 4; ++m)
      #pragma unroll
      for (int kh = 0; kh < 2; ++kh) {
        const float* ap = Ag + (m*16 + l15)*64 + kh*32 + lg*8;
        #pragma unroll
        for (int j = 0; j < 8; ++j) afr[m][kh][j] = (short)f2bf(ap[j]);
      }

    const int px0 = chunk*256 + wv*64;
    const float* xg = x + (size_t)(b*Cc + g*GC_)*HWn;
    u16* tg        = t + (size_t)(b*Cc + g*GC_)*HWn;

    #pragma unroll
    for (int nt = 0; nt < 4; ++nt) {
        const int pn = px0 + nt*16 + l15;
        short8v bfr[2];
        #pragma unroll
        for (int kh = 0; kh < 2; ++kh) {
            const float* xp = xg + (size_t)(kh*32 + lg*8)*HWn + pn;
            #pragma unroll
            for (int j = 0; j < 8; ++j) bfr[kh][j] = (short)f2bf(xp[j*HWn]);
        }
        #pragma unroll
        for (int m = 0; m < 4; ++m) {
            f32x4 acc = {0.f, 0.f, 0.f, 0.f};
            acc = __builtin_amdgcn_mfma_f32_16x16x32_bf16(afr[m][0], bfr[0], acc, 0, 0, 0);
            acc = __builtin_amdgcn_mfma_f32_16x16x32_bf16(afr[m][1], bfr[1], acc, 0, 0, 0);
            u16* tp = tg + (size_t)(m*16 + lg*4)*HWn + pn;
            #pragma unroll
            for (int r = 0; r < 4; ++r) tp[r*HWn] = f2bf(acc[r]);
        }
    }
}

// K2: S = vbox_L(t) + hbox_L(t) - t via O(1) sliding windows. bf16 in/out, f32 in LDS.
// One 32-row tile of one (b,c) image per block; XCD-swizzled so a full image
// stays on one XCD's L2 (halo rows re-used). Final S written straight from the
// horizontal pass as packed bf16x16 per thread (2x uint4, fully coalesced).
#define TROW 132
__global__ __launch_bounds__(256) void k2_cross(
    const u16* __restrict__ t, u16* __restrict__ S)
{
    __shared__ float timg[42*TROW];
    __shared__ float simg[32*TROW];
    const int tid = threadIdx.x;
    const int bid = blockIdx.x;
    const int wk = (bid & 7)*512 + (bid >> 3);    // 4096 = 8*512, bijective
    const int tile = wk & 3;
    const int bc = wk >> 2;
    const int g = (bc & 255) >> 6;
    const int p = g + 2;              // pad = {2,3,4,5}
    const int h0 = tile * 32;
    const int nrows = 32 + 2*p;
    const u16* tp = t + (size_t)bc*HWn;

    // stage t rows as f32 (ushort2 vector loads, zero-fill OOB rows)
    for (int idx = tid; idx < nrows*64; idx += 256) {
        const int r = idx >> 6, w2 = (idx & 63) << 1;
        const int hh = h0 - p + r;
        float2 v;
        if (hh >= 0 && hh < 128) {
            const ushort2 u = *(const ushort2*)(tp + (hh<<7) + w2);
            v.x = bf2f(u.x); v.y = bf2f(u.y);
        } else v = make_float2(0.f, 0.f);
        *(float2*)(timg + r*TROW + w2) = v;
    }
    __syncthreads();

    // vertical sliding box: 128 cols x 2 halves, 16 output rows each -> simg
    {
        const int w = tid & 127;
        const int half = tid >> 7;
        const int rbase = half * 16;
        float run = 0.f;
        for (int j = 0; j <= 2*p; ++j) run += timg[(rbase + j)*TROW + w];
        #pragma unroll
        for (int i = 0; i < 16; ++i) {
            simg[(rbase + i)*TROW + w] = run;
            if (i != 15)
                run += timg[(rbase + i + 1 + 2*p)*TROW + w] - timg[(rbase + i)*TROW + w];
        }
    }
    __syncthreads();

    // horizontal sliding box + combine; write final S directly (bf16 packed)
    {
        const int r8 = tid >> 3;
        const int seg = tid & 7;
        const int w0 = seg * 16;
        const float* trow = timg + (r8 + p)*TROW;
        float run = 0.f;
        const int lo = max(w0 - p, 0), hi = min(w0 + p, 127);
        for (int ww = lo; ww <= hi; ++ww) run += trow[ww];
        u16 ov[16] __attribute__((aligned(16)));
        #pragma unroll
        for (int j = 0; j < 16; ++j) {
            const int w = w0 + j;
            const float sv = simg[r8*TROW + w];
            ov[j] = f2bf(run + sv - trow[w]);
            run += (w + 1 + p < 128 ? trow[w + 1 + p] : 0.f)
                 - (w - p     >= 0  ? trow[w - p]     : 0.f);
        }
        uint4* dst = (uint4*)(S + (size_t)bc*HWn + ((h0 + r8) << 7) + w0);
        dst[0] = ((const uint4*)ov)[0];
        dst[1] = ((const uint4*)ov)[1];
    }
}

// K3: e[b,g,p] = sum_c (x_c+rq_c)(S_c+cv_c), S is bf16, planar f32 output
__global__ __launch_bounds__(256) void k3_e(
    const float* __restrict__ x, const u16* __restrict__ S,
    const float* __restrict__ r_q, const float* __restrict__ cvec,
    float* __restrict__ ebuf)
{
    const int tid = threadIdx.x;
    const int chunk = blockIdx.x & 63;
    const int g = (blockIdx.x >> 6) & 3;
    const int b = blockIdx.x >> 8;
    __shared__ float rqL[64], cvL[64];
    if (tid < 64) { rqL[tid] = r_q[g*64 + tid]; cvL[tid] = cvec[g*64 + tid]; }
    __syncthreads();
    const int p = chunk*256 + tid;
    const float* xp = x + (size_t)(b*Cc + g*GC_)*HWn + p;
    const u16*  Sp = S + (size_t)(b*Cc + g*GC_)*HWn + p;
    float acc = 0.f;
    #pragma unroll 16
    for (int c = 0; c < 64; ++c)
        acc += (xp[c*HWn] + rqL[c]) * (bf2f(Sp[c*HWn]) + cvL[c]);
    ebuf[(b*4 + g)*HWn + p] = acc;
}

// K3b: 4x4 moment matrix of e (14 scalars)
__global__ __launch_bounds__(256) void k3b_stats(
    const float* __restrict__ ebuf, float* __restrict__ stats)
{
    __shared__ float red[4*14];
    const int tid = threadIdx.x;
    const int q = blockIdx.x*256 + tid;
    const int b = q >> 14, p = q & (HWn - 1);
    const float* eb = ebuf + (size_t)b*4*HWn;
    const float e0 = eb[0*HWn + p], e1 = eb[1*HWn + p], e2 = eb[2*HWn + p], e3 = eb[3*HWn + p];
    float v[14];
    v[0]=e0; v[1]=e1; v[2]=e2; v[3]=e3;
    v[4]=e0*e0; v[5]=e0*e1; v[6]=e0*e2; v[7]=e0*e3;
    v[8]=e1*e1; v[9]=e1*e2; v[10]=e1*e3;
    v[11]=e2*e2; v[12]=e2*e3; v[13]=e3*e3;
    #pragma unroll
    for (int kk = 0; kk < 14; ++kk) {
        float s = v[kk];
        for (int off = 32; off > 0; off >>= 1) s += __shfl_down(s, off, 64);
        v[kk] = s;
    }
    const int lane = tid & 63, wv = tid >> 6;
    if (lane == 0) {
        #pragma unroll
        for (int kk = 0; kk < 14; ++kk) red[wv*14 + kk] = v[kk];
    }
    __syncthreads();
    if (tid < 14) atomicAdd(&stats[tid], red[tid] + red[14+tid] + red[28+tid] + red[42+tid]);
}

// K4: fold BN into per-channel alpha/beta
__global__ __launch_bounds__(256) void k4_stats(
    const float* __restrict__ stats, const float* __restrict__ fwred,
    const float* __restrict__ gamma, const float* __restrict__ beta,
    float* __restrict__ alpha, float* __restrict__ beta2)
{
    const int o = threadIdx.x;
    const float invN = 1.f / (float)NPIX;
    const float me0 = stats[0]*invN, me1 = stats[1]*invN, me2 = stats[2]*invN, me3 = stats[3]*invN;
    const float m00 = stats[4]*invN,  m01 = stats[5]*invN,  m02 = stats[6]*invN,  m03 = stats[7]*invN;
    const float m11 = stats[8]*invN,  m12 = stats[9]*invN,  m13 = stats[10]*invN;
    const float m22 = stats[11]*invN, m23 = stats[12]*invN, m33 = stats[13]*invN;
    const float4 fw = ((const float4*)fwred)[o];
    const float Ef = fw.x*me0 + fw.y*me1 + fw.z*me2 + fw.w*me3;
    const float E2 = fw.x*fw.x*m00 + fw.y*fw.y*m11 + fw.z*fw.z*m22 + fw.w*fw.w*m33
                   + 2.f*(fw.x*fw.y*m01 + fw.x*fw.z*m02 + fw.x*fw.w*m03
                        + fw.y*fw.z*m12 + fw.y*fw.w*m13 + fw.z*fw.w*m23);
    const float var = E2 - Ef*Ef;
    const float a = gamma[o] * rsqrtf(var + EPS);
    alpha[o] = a;
    beta2[o] = beta[o] - Ef*a;
}

// K5: out = x * sigmoid(relu(alpha[o]*(fwred[o]·e) + beta2[o]))
__global__ __launch_bounds__(256) void k5_out(
    const float* __restrict__ x, const float* __restrict__ ebuf,
    const float* __restrict__ fwred, const float* __restrict__ alpha,
    const float* __restrict__ beta2, float* __restrict__ out)
{
    const int chunk = blockIdx.x & 15;
    const int o = (blockIdx.x >> 4) & 255;
    const int b = blockIdx.x >> 12;
    const float4 fw = ((const float4*)fwred)[o];
    const float al = alpha[o], be = beta2[o];
    const int p0 = chunk*1024 + threadIdx.x*4;
    const float* eb = ebuf + (size_t)b*4*HWn;
    const float4 E0 = *(const float4*)(eb + 0*HWn + p0);
    const float4 E1 = *(const float4*)(eb + 1*HWn + p0);
    const float4 E2 = *(const float4*)(eb + 2*HWn + p0);
    const float4 E3 = *(const float4*)(eb + 3*HWn + p0);
    const size_t base = (size_t)(b*Cc + o)*HWn + p0;
    const float4 xv = *(const float4*)(x + base);
    float f[4], xa[4] = {xv.x, xv.y, xv.z, xv.w};
    f[0] = fw.x*E0.x + fw.y*E1.x + fw.z*E2.x + fw.w*E3.x;
    f[1] = fw.x*E0.y + fw.y*E1.y + fw.z*E2.y + fw.w*E3.y;
    f[2] = fw.x*E0.z + fw.y*E1.z + fw.z*E2.z + fw.w*E3.z;
    f[3] = fw.x*E0.w + fw.y*E1.w + fw.z*E2.w + fw.w*E3.w;
    float4 r;
    float* rp = &r.x;
    #pragma unroll
    for (int j = 0; j < 4; ++j) {
        float z = al*f[j] + be;
        z = fmaxf(z, 0.f);
        rp[j] = xa[j] / (1.f + __expf(-z));
    }
    *(float4*)(out + base) = r;
}

extern "C" void kernel_launch(void* const* d_in, const int* in_sizes, int n_in,
                              void* d_out, int out_size, void* d_ws, size_t ws_size,
                              hipStream_t stream)
{
    const float* x   = (const float*)d_in[0];
    const float* qw  = (const float*)d_in[1];
    const float* kw  = (const float*)d_in[2];
    const float* r_q = (const float*)d_in[3];
    const float* rk0 = (const float*)d_in[4];
    const float* rk1 = (const float*)d_in[5];
    const float* rk2 = (const float*)d_in[6];
    const float* rk3 = (const float*)d_in[7];
    const float* fw  = (const float*)d_in[8];
    const float* gm  = (const float*)d_in[9];
    const float* bt  = (const float*)d_in[10];
    float* out = (float*)d_out;
    float* ws  = (float*)d_ws;

    u16*   t     = (u16*)(ws + T_OFF);      // bf16, 33.5 MB
    float* ebuf  = ws + E_OFF;
    float* stats = ws + ST_OFF;
    float* A     = ws + A_OFF;
    float* cvec  = ws + CV_OFF;
    float* fwr   = ws + FW_OFF;
    float* alpha = ws + ALP_OFF;
    float* beta2 = ws + BET_OFF;
    u16*   Sbuf  = (u16*)out;               // S staged bf16 in d_out, overwritten by k5

    hipMemsetAsync(stats, 0, 16*sizeof(float), stream);
    k0_precompute<<<5,     256, 0, stream>>>(qw, kw, rk0, rk1, rk2, rk3, fw, A, cvec, fwr);
    k1_mfma      <<<1024,  256, 0, stream>>>(x, A, t);
    k2_cross     <<<4096,  256, 0, stream>>>(t, Sbuf);
    k3_e         <<<1024,  256, 0, stream>>>(x, Sbuf, r_q, cvec, ebuf);
    k3b_stats    <<<256,   256, 0, stream>>>(ebuf, stats);
    k4_stats     <<<1,     256, 0, stream>>>(stats, fwr, gm, bt, alpha, beta2);
    k5_out       <<<16384, 256, 0, stream>>>(x, ebuf, fwr, alpha, beta2, out);
}

// Round 5
// 116.699 us; speedup vs baseline: 2.3980x; 1.1561x over previous
//
#include <hip/hip_runtime.h>

#define Bb 4
#define Cc 256
#define GC_ 64
#define Hh 128
#define Wd 128
#define HWn 16384
#define NPIX 65536
#define EPS 1e-5f

// workspace layout (float offsets). t is bf16 (uses half its region).
#define T_OFF   0
#define E_OFF   16777216
#define ST_OFF  (E_OFF + NPIX*4)
#define A_OFF   (ST_OFF + 16)
#define CV_OFF  (A_OFF + 16384)
#define FW_OFF  (CV_OFF + 256)
#define ALP_OFF (FW_OFF + 1024)
#define BET_OFF (ALP_OFF + 256)

typedef __attribute__((ext_vector_type(8))) short short8v;
typedef __attribute__((ext_vector_type(4))) float f32x4;
typedef unsigned short u16;

__device__ inline u16 f2bf(float f) {
    union { float f; unsigned u; } v; v.f = f;
    unsigned r = v.u + 0x7fff + ((v.u >> 16) & 1);   // RNE
    return (u16)(r >> 16);
}
__device__ inline float bf2f(u16 u) {
    union { unsigned u; float f; } v; v.u = ((unsigned)u) << 16;
    return v.f;
}

// K0: A_g = qw_g^T @ kw_g ; cvec_g = qw_g^T (sum_r rk_g) ; fwred[o][i] = sum_c fusion_w[o, i*64+c]
// block 4 also zeroes stats (replaces the memset dispatch).
__global__ __launch_bounds__(256) void k0_precompute(
    const float* __restrict__ qw, const float* __restrict__ kw,
    const float* __restrict__ rk0, const float* __restrict__ rk1,
    const float* __restrict__ rk2, const float* __restrict__ rk3,
    const float* __restrict__ fusion_w,
    float* __restrict__ A, float* __restrict__ cvec, float* __restrict__ fwred,
    float* __restrict__ stats)
{
    const int tid = threadIdx.x;
    if (blockIdx.x == 4) {
        if (tid < 16) stats[tid] = 0.f;
        for (int i = 0; i < 4; ++i) {
            float s = 0.f;
            const float* fp = fusion_w + tid*256 + i*64;
            #pragma unroll 8
            for (int c = 0; c < 64; ++c) s += fp[c];
            fwred[tid*4 + i] = s;
        }
        return;
    }
    const int g = blockIdx.x;
    __shared__ float qwL[4096];
    __shared__ float kwL[4096];
    __shared__ float rks[64];
    for (int i = tid; i < 4096; i += 256) {
        qwL[i] = qw[g*4096 + i];
        kwL[i] = kw[g*4096 + i];
    }
    __syncthreads();
    if (tid < 64) {
        const float* rkp = (g==0)?rk0:(g==1)?rk1:(g==2)?rk2:rk3;
        const int R = 4*g + 9;               // 2L-1 for L={5,7,9,11}
        float s = 0.f;
        for (int r = 0; r < R; ++r) s += rkp[tid*R + r];
        rks[tid] = s;
    }
    __syncthreads();
    for (int idx = tid; idx < 4096; idx += 256) {
        const int c = idx >> 6, d = idx & 63;
        float s = 0.f;
        #pragma unroll
        for (int o = 0; o < 64; ++o) s += qwL[o*64 + c] * kwL[o*64 + d];
        A[g*4096 + idx] = s;
    }
    if (tid < 64) {
        float s = 0.f;
        #pragma unroll
        for (int o = 0; o < 64; ++o) s += qwL[o*64 + tid] * rks[o];
        cvec[g*64 + tid] = s;
    }
}

// K1 (MFMA, swapped operands): t[b, g*64+o, p] = sum_d A_g[o][d] * x[b, g*64+d, p]
// Compute D = Xfrag(A-op) * Afrag(B-op): D row = pixel, col = channel.
// Lane holds 4 CONSECUTIVE pixels (r=0..3) of channel (l&15) -> one uint2 (4xbf16) store.
__global__ __launch_bounds__(256) void k1_mfma(
    const float* __restrict__ x, const float* __restrict__ A, u16* __restrict__ t)
{
    const int tid = threadIdx.x;
    const int wv = tid >> 6, lane = tid & 63;
    const int chunk = blockIdx.x & 63;
    const int g = (blockIdx.x >> 6) & 3;
    const int b = blockIdx.x >> 8;
    const int l15 = lane & 15, lg = lane >> 4;

    const float* Ag = A + g*4096;
    short8v afr[4][2];   // Ag[ct*16+l15][kh*32+lg*8+j]  (B-operand now)
    #pragma unroll
    for (int ct = 0; ct < 4; ++ct)
      #pragma unroll
      for (int kh = 0; kh < 2; ++kh) {
        const float* ap = Ag + (ct*16 + l15)*64 + kh*32 + lg*8;
        #pragma unroll
        for (int j = 0; j < 8; ++j) afr[ct][kh][j] = (short)f2bf(ap[j]);
      }

    const int px0 = chunk*256 + wv*64;
    const float* xg = x + (size_t)(b*Cc + g*GC_)*HWn;
    u16* tg        = t + (size_t)(b*Cc + g*GC_)*HWn;

    #pragma unroll
    for (int nt = 0; nt < 4; ++nt) {
        const int pn = px0 + nt*16 + l15;
        short8v bfr[2];  // X[kh*32+lg*8+j][pn]  (A-operand now)
        #pragma unroll
        for (int kh = 0; kh < 2; ++kh) {
            const float* xp = xg + (size_t)(kh*32 + lg*8)*HWn + pn;
            #pragma unroll
            for (int j = 0; j < 8; ++j) bfr[kh][j] = (short)f2bf(xp[j*HWn]);
        }
        #pragma unroll
        for (int ct = 0; ct < 4; ++ct) {
            f32x4 acc = {0.f, 0.f, 0.f, 0.f};
            acc = __builtin_amdgcn_mfma_f32_16x16x32_bf16(bfr[0], afr[ct][0], acc, 0, 0, 0);
            acc = __builtin_amdgcn_mfma_f32_16x16x32_bf16(bfr[1], afr[ct][1], acc, 0, 0, 0);
            // lane: channel ct*16+l15, pixels px0+nt*16+lg*4 .. +3
            u16 ov[4] __attribute__((aligned(8)));
            #pragma unroll
            for (int r = 0; r < 4; ++r) ov[r] = f2bf(acc[r]);
            *(uint2*)(tg + (size_t)(ct*16 + l15)*HWn + px0 + nt*16 + lg*4) = *(const uint2*)ov;
        }
    }
}

// K2: S = vbox_L(t) + hbox_L(t) - t via O(1) sliding windows. bf16 LDS (19.5KB -> 8 blocks/CU).
#define TROW 132
__global__ __launch_bounds__(256) void k2_cross(
    const u16* __restrict__ t, u16* __restrict__ S)
{
    __shared__ u16 timg[42*TROW];
    __shared__ u16 simg[32*TROW];
    const int tid = threadIdx.x;
    const int bid = blockIdx.x;
    const int wk = (bid & 7)*512 + (bid >> 3);    // 4096 = 8*512, bijective
    const int tile = wk & 3;
    const int bc = wk >> 2;
    const int g = (bc & 255) >> 6;
    const int p = g + 2;              // pad = {2,3,4,5}
    const int h0 = tile * 32;
    const int nrows = 32 + 2*p;
    const u16* tp = t + (size_t)bc*HWn;

    // stage t rows (uint2 = 4xbf16 vector loads, zero-fill OOB rows)
    for (int idx = tid; idx < nrows*32; idx += 256) {
        const int r = idx >> 5, w4 = (idx & 31) << 2;
        const int hh = h0 - p + r;
        uint2 v = make_uint2(0u, 0u);
        if (hh >= 0 && hh < 128) v = *(const uint2*)(tp + (hh<<7) + w4);
        *(uint2*)(timg + r*TROW + w4) = v;
    }
    __syncthreads();

    // vertical sliding box: 128 cols x 2 halves, 16 output rows each -> simg (bf16)
    {
        const int w = tid & 127;
        const int half = tid >> 7;
        const int rbase = half * 16;
        float run = 0.f;
        for (int j = 0; j <= 2*p; ++j) run += bf2f(timg[(rbase + j)*TROW + w]);
        #pragma unroll
        for (int i = 0; i < 16; ++i) {
            simg[(rbase + i)*TROW + w] = f2bf(run);
            if (i != 15)
                run += bf2f(timg[(rbase + i + 1 + 2*p)*TROW + w])
                     - bf2f(timg[(rbase + i)*TROW + w]);
        }
    }
    __syncthreads();

    // horizontal sliding box + combine; write final S directly (bf16 packed)
    {
        const int r8 = tid >> 3;
        const int seg = tid & 7;
        const int w0 = seg * 16;
        const u16* trow = timg + (r8 + p)*TROW;
        float run = 0.f;
        const int lo = max(w0 - p, 0), hi = min(w0 + p, 127);
        for (int ww = lo; ww <= hi; ++ww) run += bf2f(trow[ww]);
        u16 ov[16] __attribute__((aligned(16)));
        #pragma unroll
        for (int j = 0; j < 16; ++j) {
            const int w = w0 + j;
            const float sv = bf2f(simg[r8*TROW + w]);
            ov[j] = f2bf(run + sv - bf2f(trow[w]));
            run += (w + 1 + p < 128 ? bf2f(trow[w + 1 + p]) : 0.f)
                 - (w - p     >= 0  ? bf2f(trow[w - p])     : 0.f);
        }
        uint4* dst = (uint4*)(S + (size_t)bc*HWn + ((h0 + r8) << 7) + w0);
        dst[0] = ((const uint4*)ov)[0];
        dst[1] = ((const uint4*)ov)[1];
    }
}

// K3: e[b,g,p] = sum_c (x_c+rq_c)(S_c+cv_c), S is bf16, planar f32 output
__global__ __launch_bounds__(256) void k3_e(
    const float* __restrict__ x, const u16* __restrict__ S,
    const float* __restrict__ r_q, const float* __restrict__ cvec,
    float* __restrict__ ebuf)
{
    const int tid = threadIdx.x;
    const int chunk = blockIdx.x & 63;
    const int g = (blockIdx.x >> 6) & 3;
    const int b = blockIdx.x >> 8;
    __shared__ float rqL[64], cvL[64];
    if (tid < 64) { rqL[tid] = r_q[g*64 + tid]; cvL[tid] = cvec[g*64 + tid]; }
    __syncthreads();
    const int p = chunk*256 + tid;
    const float* xp = x + (size_t)(b*Cc + g*GC_)*HWn + p;
    const u16*  Sp = S + (size_t)(b*Cc + g*GC_)*HWn + p;
    float acc = 0.f;
    #pragma unroll 16
    for (int c = 0; c < 64; ++c)
        acc += (xp[c*HWn] + rqL[c]) * (bf2f(Sp[c*HWn]) + cvL[c]);
    ebuf[(b*4 + g)*HWn + p] = acc;
}

// K3b: 4x4 moment matrix of e (14 scalars)
__global__ __launch_bounds__(256) void k3b_stats(
    const float* __restrict__ ebuf, float* __restrict__ stats)
{
    __shared__ float red[4*14];
    const int tid = threadIdx.x;
    const int q = blockIdx.x*256 + tid;
    const int b = q >> 14, p = q & (HWn - 1);
    const float* eb = ebuf + (size_t)b*4*HWn;
    const float e0 = eb[0*HWn + p], e1 = eb[1*HWn + p], e2 = eb[2*HWn + p], e3 = eb[3*HWn + p];
    float v[14];
    v[0]=e0; v[1]=e1; v[2]=e2; v[3]=e3;
    v[4]=e0*e0; v[5]=e0*e1; v[6]=e0*e2; v[7]=e0*e3;
    v[8]=e1*e1; v[9]=e1*e2; v[10]=e1*e3;
    v[11]=e2*e2; v[12]=e2*e3; v[13]=e3*e3;
    #pragma unroll
    for (int kk = 0; kk < 14; ++kk) {
        float s = v[kk];
        for (int off = 32; off > 0; off >>= 1) s += __shfl_down(s, off, 64);
        v[kk] = s;
    }
    const int lane = tid & 63, wv = tid >> 6;
    if (lane == 0) {
        #pragma unroll
        for (int kk = 0; kk < 14; ++kk) red[wv*14 + kk] = v[kk];
    }
    __syncthreads();
    if (tid < 14) atomicAdd(&stats[tid], red[tid] + red[14+tid] + red[28+tid] + red[42+tid]);
}

// K4: fold BN into per-channel alpha/beta
__global__ __launch_bounds__(256) void k4_stats(
    const float* __restrict__ stats, const float* __restrict__ fwred,
    const float* __restrict__ gamma, const float* __restrict__ beta,
    float* __restrict__ alpha, float* __restrict__ beta2)
{
    const int o = threadIdx.x;
    const float invN = 1.f / (float)NPIX;
    const float me0 = stats[0]*invN, me1 = stats[1]*invN, me2 = stats[2]*invN, me3 = stats[3]*invN;
    const float m00 = stats[4]*invN,  m01 = stats[5]*invN,  m02 = stats[6]*invN,  m03 = stats[7]*invN;
    const float m11 = stats[8]*invN,  m12 = stats[9]*invN,  m13 = stats[10]*invN;
    const float m22 = stats[11]*invN, m23 = stats[12]*invN, m33 = stats[13]*invN;
    const float4 fw = ((const float4*)fwred)[o];
    const float Ef = fw.x*me0 + fw.y*me1 + fw.z*me2 + fw.w*me3;
    const float E2 = fw.x*fw.x*m00 + fw.y*fw.y*m11 + fw.z*fw.z*m22 + fw.w*fw.w*m33
                   + 2.f*(fw.x*fw.y*m01 + fw.x*fw.z*m02 + fw.x*fw.w*m03
                        + fw.y*fw.z*m12 + fw.y*fw.w*m13 + fw.z*fw.w*m23);
    const float var = E2 - Ef*Ef;
    const float a = gamma[o] * rsqrtf(var + EPS);
    alpha[o] = a;
    beta2[o] = beta[o] - Ef*a;
}

// K5: out = x * sigmoid(relu(alpha[o]*(fwred[o]·e) + beta2[o]))
__global__ __launch_bounds__(256) void k5_out(
    const float* __restrict__ x, const float* __restrict__ ebuf,
    const float* __restrict__ fwred, const float* __restrict__ alpha,
    const float* __restrict__ beta2, float* __restrict__ out)
{
    const int chunk = blockIdx.x & 15;
    const int o = (blockIdx.x >> 4) & 255;
    const int b = blockIdx.x >> 12;
    const float4 fw = ((const float4*)fwred)[o];
    const float al = alpha[o], be = beta2[o];
    const int p0 = chunk*1024 + threadIdx.x*4;
    const float* eb = ebuf + (size_t)b*4*HWn;
    const float4 E0 = *(const float4*)(eb + 0*HWn + p0);
    const float4 E1 = *(const float4*)(eb + 1*HWn + p0);
    const float4 E2 = *(const float4*)(eb + 2*HWn + p0);
    const float4 E3 = *(const float4*)(eb + 3*HWn + p0);
    const size_t base = (size_t)(b*Cc + o)*HWn + p0;
    const float4 xv = *(const float4*)(x + base);
    float f[4], xa[4] = {xv.x, xv.y, xv.z, xv.w};
    f[0] = fw.x*E0.x + fw.y*E1.x + fw.z*E2.x + fw.w*E3.x;
    f[1] = fw.x*E0.y + fw.y*E1.y + fw.z*E2.y + fw.w*E3.y;
    f[2] = fw.x*E0.z + fw.y*E1.z + fw.z*E2.z + fw.w*E3.z;
    f[3] = fw.x*E0.w + fw.y*E1.w + fw.z*E2.w + fw.w*E3.w;
    float4 r;
    float* rp = &r.x;
    #pragma unroll
    for (int j = 0; j < 4; ++j) {
        float z = al*f[j] + be;
        z = fmaxf(z, 0.f);
        rp[j] = xa[j] / (1.f + __expf(-z));
    }
    *(float4*)(out + base) = r;
}

extern "C" void kernel_launch(void* const* d_in, const int* in_sizes, int n_in,
                              void* d_out, int out_size, void* d_ws, size_t ws_size,
                              hipStream_t stream)
{
    const float* x   = (const float*)d_in[0];
    const float* qw  = (const float*)d_in[1];
    const float* kw  = (const float*)d_in[2];
    const float* r_q = (const float*)d_in[3];
    const float* rk0 = (const float*)d_in[4];
    const float* rk1 = (const float*)d_in[5];
    const float* rk2 = (const float*)d_in[6];
    const float* rk3 = (const float*)d_in[7];
    const float* fw  = (const float*)d_in[8];
    const float* gm  = (const float*)d_in[9];
    const float* bt  = (const float*)d_in[10];
    float* out = (float*)d_out;
    float* ws  = (float*)d_ws;

    u16*   t     = (u16*)(ws + T_OFF);      // bf16, 33.5 MB
    float* ebuf  = ws + E_OFF;
    float* stats = ws + ST_OFF;
    float* A     = ws + A_OFF;
    float* cvec  = ws + CV_OFF;
    float* fwr   = ws + FW_OFF;
    float* alpha = ws + ALP_OFF;
    float* beta2 = ws + BET_OFF;
    u16*   Sbuf  = (u16*)out;               // S staged bf16 in d_out, overwritten by k5

    k0_precompute<<<5,     256, 0, stream>>>(qw, kw, rk0, rk1, rk2, rk3, fw, A, cvec, fwr, stats);
    k1_mfma      <<<1024,  256, 0, stream>>>(x, A, t);
    k2_cross     <<<4096,  256, 0, stream>>>(t, Sbuf);
    k3_e         <<<1024,  256, 0, stream>>>(x, Sbuf, r_q, cvec, ebuf);
    k3b_stats    <<<256,   256, 0, stream>>>(ebuf, stats);
    k4_stats     <<<1,     256, 0, stream>>>(stats, fwr, gm, bt, alpha, beta2);
    k5_out       <<<16384, 256, 0, stream>>>(x, ebuf, fwr, alpha, beta2, out);
}